// Round 21
// baseline (87.841 us; speedup 1.0000x reference)
//
#include <hip/hip_runtime.h>
#include <hip/hip_bf16.h>
#include <math.h>

#define NB 4
#define NC 512
#define NN 4096
#define NK 20
#define NCP 128
#define SPLIT 4
#define CHUNK (NN / SPLIT)   // 1024 keys per split
#define NTILES (CHUNK / 64)  // 16

typedef __bf16 bf16x8 __attribute__((ext_vector_type(8)));
typedef float f32x4 __attribute__((ext_vector_type(4)));
typedef float f32x16 __attribute__((ext_vector_type(16)));
typedef short short8 __attribute__((ext_vector_type(8)));
typedef unsigned int uint4v __attribute__((ext_vector_type(4)));

static __device__ __forceinline__ unsigned short f2bf(float f) {
    unsigned int u = __builtin_bit_cast(unsigned int, f);
    unsigned int r = (u + 0x7FFFu + ((u >> 16) & 1u)) >> 16;
    return (unsigned short)r;
}
static __device__ __forceinline__ float bf2f(unsigned short h) {
    unsigned int u = ((unsigned int)h) << 16;
    return __builtin_bit_cast(float, u);
}
static __device__ __forceinline__ bf16x8 ldbf8(const unsigned short* p) {
    return __builtin_bit_cast(bf16x8, *reinterpret_cast<const short8*>(p));
}
static __device__ __forceinline__ void gld16(const unsigned short* g, unsigned short* l) {
    __builtin_amdgcn_global_load_lds(
        (const __attribute__((address_space(1))) unsigned int*)g,
        (__attribute__((address_space(3))) unsigned int*)l, 16, 0, 0);
}
static __device__ __forceinline__ unsigned int cvtpk(float lo, float hi) {
    unsigned int r;
    asm("v_cvt_pk_bf16_f32 %0, %1, %2" : "=v"(r) : "v"(lo), "v"(hi));
    return r;
}

#define MFMA16(a, b, c) __builtin_amdgcn_mfma_f32_16x16x32_bf16(a, b, c, 0, 0, 0)
#define MFMA32(a, b, c) __builtin_amdgcn_mfma_f32_32x32x16_bf16(a, b, c, 0, 0, 0)
#define SCHED0() __builtin_amdgcn_sched_barrier(0)
#define BAR() do { SCHED0(); __builtin_amdgcn_s_barrier(); SCHED0(); } while (0)

// ---------------- proj: fp[b][n][d] = sum_c feat[b][c][n]*w[d][c] + bias[d] ----
// 32 n-rows per block -> grid 512 = 2 blocks/CU (w-reuse optimum). Block (0,0) zeroes ct.
__global__ __launch_bounds__(256) void proj_kernel(
    const float* __restrict__ feat, const float* __restrict__ w,
    const float* __restrict__ bias, unsigned short* __restrict__ fp,
    unsigned short* __restrict__ fpT, float* __restrict__ ctg)
{
    const int b = blockIdx.y;
    const int n0 = blockIdx.x * 32;
    const int tid = threadIdx.x;
    const int wid = tid >> 6;
    const int lane = tid & 63;
    const int lg = lane >> 4, lr = lane & 15;

    if (blockIdx.x == 0 && blockIdx.y == 0) {
        #pragma unroll
        for (int i = 0; i < (NB * NK * NCP) / 256; ++i)
            ctg[i * 256 + tid] = 0.f;
    }

    __shared__ unsigned short lds_f[2][32][40];   // dbuf [n][c] bf16, +8 pad

    const float* featb = feat + (size_t)b * NC * NN;

    f32x4 acc[2][2];
    #pragma unroll
    for (int i = 0; i < 2; ++i)
        #pragma unroll
        for (int j = 0; j < 2; ++j) acc[i][j] = (f32x4){0.f, 0.f, 0.f, 0.f};

    const int cc = tid >> 3, q = tid & 7;
    float4 pre = *reinterpret_cast<const float4*>(&featb[(size_t)cc * NN + n0 + q * 4]);

    for (int c0 = 0; c0 < NC; c0 += 32) {
        const int cur = (c0 >> 5) & 1;
        lds_f[cur][q * 4 + 0][cc] = f2bf(pre.x);
        lds_f[cur][q * 4 + 1][cc] = f2bf(pre.y);
        lds_f[cur][q * 4 + 2][cc] = f2bf(pre.z);
        lds_f[cur][q * 4 + 3][cc] = f2bf(pre.w);
        __syncthreads();
        if (c0 + 32 < NC)
            pre = *reinterpret_cast<const float4*>(
                &featb[(size_t)(c0 + 32 + cc) * NN + n0 + q * 4]);
        bf16x8 afr[2];
        #pragma unroll
        for (int dt = 0; dt < 2; ++dt) {
            const float4* wr = reinterpret_cast<const float4*>(
                w + (size_t)(wid * 32 + dt * 16 + lr) * NC + c0 + lg * 8);
            float4 w0 = wr[0], w1 = wr[1];
            short8 a;
            a[0] = (short)f2bf(w0.x); a[1] = (short)f2bf(w0.y);
            a[2] = (short)f2bf(w0.z); a[3] = (short)f2bf(w0.w);
            a[4] = (short)f2bf(w1.x); a[5] = (short)f2bf(w1.y);
            a[6] = (short)f2bf(w1.z); a[7] = (short)f2bf(w1.w);
            afr[dt] = __builtin_bit_cast(bf16x8, a);
        }
        #pragma unroll
        for (int n1 = 0; n1 < 2; ++n1) {
            bf16x8 bfr = ldbf8(&lds_f[cur][n1 * 16 + lr][lg * 8]);
            #pragma unroll
            for (int dt = 0; dt < 2; ++dt)
                acc[dt][n1] = MFMA16(afr[dt], bfr, acc[dt][n1]);
        }
    }
    #pragma unroll
    for (int dt = 0; dt < 2; ++dt)
        #pragma unroll
        for (int n1 = 0; n1 < 2; ++n1)
            #pragma unroll
            for (int i = 0; i < 4; ++i) {
                int d = wid * 32 + dt * 16 + lg * 4 + i;
                int n = n0 + n1 * 16 + lr;
                unsigned short h = f2bf(acc[dt][n1][i] + bias[d]);
                fp[((size_t)b * NN + n) * NCP + d] = h;
                fpT[((size_t)b * NCP + d) * NN + n] = h;
            }
}

// ---------------- attention partials + fused class_term ----------------
// 256 threads = 4 waves; wave owns 32 q-rows; 32x32x16 MFMA; R6 structure.
// Softmax in exp2 domain: Q pre-scaled by log2(e) at load, so MFMA emits
// S*log2e and softmax uses native v_exp_f32 with no per-element multiply.
// Fused ct: cam in LDS; ct loads+FMAs after PV. Final-tile drain removed.
__global__ __launch_bounds__(256, 2) void attn_partial_kernel(
    const unsigned short* __restrict__ fp, const unsigned short* __restrict__ fpT,
    const float* __restrict__ cam, float* __restrict__ ctg,
    unsigned short* __restrict__ po, float* __restrict__ mbuf, float* __restrict__ lbuf)
{
    const int b = blockIdx.z;
    const int sidx = blockIdx.y;
    const int tid = threadIdx.x;
    const int wid = tid >> 6;
    const int lane = tid & 63;
    const int l31 = lane & 31, hi = lane >> 5;
    const int q0 = blockIdx.x * 128 + wid * 32;
    const int kvbase = sidx * CHUNK;

    __shared__ unsigned short kt[2][64 * 128];   // K dbuf: [kv][d], 16-chunk XOR (rk&15)
    __shared__ unsigned short vt[2][64 * 128];   // V dbuf: pair-rows [d>>1][256B], XOR (rowp&15)
    __shared__ float cam_lds[CHUNK];             // 4 KB cam chunk for fused ct

    const unsigned short* fpb  = fp  + (size_t)b * NN * NCP;
    const unsigned short* fpTb = fpT + (size_t)b * NCP * NN;

    const bool doCT = (blockIdx.x < NK);
    const int pd = tid & 63;          // d-pair index: d = 2*pd, 2*pd+1
    const int qtr = tid >> 6;         // n quarter within a 64-kv tile
    float ctx = 0.f, cty = 0.f;

    if (doCT) {
        const float* camb = cam + ((size_t)b * NK + blockIdx.x) * NN + kvbase;
        *reinterpret_cast<float4*>(&cam_lds[tid * 4]) =
            *reinterpret_cast<const float4*>(&camb[tid * 4]);
    }

    int offK[4], offV[4];
    #pragma unroll
    for (int i = 0; i < 4; ++i) {
        int oc = i * 256 + tid;
        int rk = oc >> 4, ck = oc & 15;
        offK[i] = rk * NCP + ((ck ^ (rk & 15)) << 3);
        int rowp = oc >> 4, cv = oc & 15;
        int cg = cv ^ (rowp & 15);
        int d = rowp * 2 + (cg >> 3), kvc = cg & 7;
        offV[i] = d * NN + (kvc << 3);
    }

    // Q fragments pre-scaled by log2(e): MFMA output = S * log2e
    const float LOG2E = 1.44269504f;
    bf16x8 qf[8];
    #pragma unroll
    for (int kk = 0; kk < 8; ++kk) {
        short8 raw = *reinterpret_cast<const short8*>(
            &fpb[(size_t)(q0 + l31) * NCP + kk * 16 + hi * 8]);
        uint4v u;
        #pragma unroll
        for (int p = 0; p < 4; ++p) {
            float lo = bf2f((unsigned short)raw[2 * p]) * LOG2E;
            float hh = bf2f((unsigned short)raw[2 * p + 1]) * LOG2E;
            u[p] = cvtpk(lo, hh);
        }
        qf[kk] = __builtin_bit_cast(bf16x8, u);
    }

    f32x16 o[4];
    #pragma unroll
    for (int dt = 0; dt < 4; ++dt)
        #pragma unroll
        for (int j = 0; j < 16; ++j) o[dt][j] = 0.f;
    float m_i = -INFINITY, l_i = 0.f;

    {
        const unsigned short* k0 = fpb + (size_t)kvbase * NCP;
        const unsigned short* v0 = fpTb + kvbase;
        #pragma unroll
        for (int i = 0; i < 4; ++i) {
            gld16(k0 + offK[i], &kt[0][(i * 256 + wid * 64) * 8]);
            gld16(v0 + offV[i], &vt[0][(i * 256 + wid * 64) * 8]);
        }
    }
    SCHED0();
    __syncthreads();   // drains vm+lgkm (staging + cam_lds writes) and barriers

    for (int t = 0; t < NTILES; ++t) {
        const int cur = t & 1;
        // ---- issue next-tile stages (guarded: no wasted wrap-around) ----
        if (t + 1 < NTILES) {
            const unsigned short* knext = fpb + (size_t)(kvbase + (t + 1) * 64) * NCP;
            const unsigned short* vnext = fpTb + kvbase + (t + 1) * 64;
            #pragma unroll
            for (int i = 0; i < 4; ++i) {
                gld16(knext + offK[i], &kt[cur ^ 1][(i * 256 + wid * 64) * 8]);
                gld16(vnext + offV[i], &vt[cur ^ 1][(i * 256 + wid * 64) * 8]);
            }
        }
        SCHED0();
        // ---- S^T = K Q^T (in log2e-scaled domain) ----
        const unsigned short* ktc = &kt[cur][0];
        f32x16 s[2];
        #pragma unroll
        for (int g = 0; g < 2; ++g)
            #pragma unroll
            for (int j = 0; j < 16; ++j) s[g][j] = 0.f;
        __builtin_amdgcn_s_setprio(1);
        #pragma unroll
        for (int kk = 0; kk < 8; ++kk) {
            #pragma unroll
            for (int g = 0; g < 2; ++g) {
                int row = g * 32 + l31;
                bf16x8 kf = ldbf8(&ktc[row * 128 + (((kk * 2 + hi) ^ (row & 15)) << 3)]);
                s[g] = MFMA32(kf, qf[kk], s[g]);
            }
        }
        __builtin_amdgcn_s_setprio(0);
        // ---- online softmax (exp2 domain): lane owns q = l31 ----
        float pmax = s[0][0];
        #pragma unroll
        for (int g = 0; g < 2; ++g)
            #pragma unroll
            for (int j = 0; j < 16; ++j) pmax = fmaxf(pmax, s[g][j]);
        pmax = fmaxf(pmax, __shfl_xor(pmax, 32));
        if (!__all(pmax - m_i <= 8.f)) {   // defer-max (THR=8 in log2 units)
            float mnew = fmaxf(m_i, pmax);
            float sc = exp2f(m_i - mnew);
            l_i *= sc;
            #pragma unroll
            for (int dt = 0; dt < 4; ++dt)
                #pragma unroll
                for (int j = 0; j < 16; ++j) o[dt][j] *= sc;
            m_i = mnew;
        }
        float sum = 0.f;
        #pragma unroll
        for (int g = 0; g < 2; ++g)
            #pragma unroll
            for (int j = 0; j < 16; ++j) {
                float e = exp2f(s[g][j] - m_i);
                s[g][j] = e;
                sum += e;
            }
        sum += __shfl_xor(sum, 32);
        l_i += sum;
        // ---- P^T -> bf16 words -> register exchange (8 permlane32_swap) ----
        unsigned int wk[2][8];
        #pragma unroll
        for (int g = 0; g < 2; ++g)
            #pragma unroll
            for (int m = 0; m < 8; ++m)
                wk[g][m] = cvtpk(s[g][2 * m], s[g][2 * m + 1]);
        bf16x8 pf[4];
        #pragma unroll
        for (int g = 0; g < 2; ++g)
            #pragma unroll
            for (int sub = 0; sub < 2; ++sub) {
                unsigned int A0 = wk[g][4 * sub],     B0 = wk[g][4 * sub + 2];
                unsigned int A1 = wk[g][4 * sub + 1], B1 = wk[g][4 * sub + 3];
                asm("v_permlane32_swap_b32 %0, %1" : "+v"(A0), "+v"(B0));
                asm("v_permlane32_swap_b32 %0, %1" : "+v"(A1), "+v"(B1));
                uint4v u;
                u[0] = A0; u[1] = A1; u[2] = B0; u[3] = B1;
                pf[2 * g + sub] = __builtin_bit_cast(bf16x8, u);
            }
        // ---- O^T += V^T P^T ----
        const unsigned short* vtc = &vt[cur][0];
        __builtin_amdgcn_s_setprio(1);
        #pragma unroll
        for (int c2 = 0; c2 < 4; ++c2) {
            #pragma unroll
            for (int dt = 0; dt < 4; ++dt) {
                int row32 = dt * 32 + l31;
                int rowp = row32 >> 1;
                int chunk = (row32 & 1) * 8 + c2 * 2 + hi;
                bf16x8 vf = ldbf8(&vtc[rowp * 128 + ((chunk ^ (rowp & 15)) << 3)]);
                o[dt] = MFMA32(vf, pf[c2], o[dt]);
            }
        }
        __builtin_amdgcn_s_setprio(0);
        // ---- fused ct accumulation (cam from LDS, executes under MFMA drain) ----
        if (doCT) {
            float cf[16];
            const float4* cl = reinterpret_cast<const float4*>(&cam_lds[t * 64 + qtr * 16]);
            #pragma unroll
            for (int v4 = 0; v4 < 4; ++v4) {
                float4 c4 = cl[v4];
                cf[v4 * 4 + 0] = c4.x; cf[v4 * 4 + 1] = c4.y;
                cf[v4 * 4 + 2] = c4.z; cf[v4 * 4 + 3] = c4.w;
            }
            const int c8 = pd >> 2, de = (pd * 2) & 7;
            #pragma unroll
            for (int n = 0; n < 16; ++n) {
                int rown = qtr * 16 + n;
                unsigned int v = *reinterpret_cast<const unsigned int*>(
                    &ktc[rown * 128 + ((c8 ^ (rown & 15)) << 3) + de]);
                ctx += cf[n] * bf2f((unsigned short)(v & 0xffff));
                cty += cf[n] * bf2f((unsigned short)(v >> 16));
            }
        }
        SCHED0();
        if (t + 1 < NTILES) {   // final tile: nothing staged, no drain needed
            asm volatile("s_waitcnt vmcnt(0)" ::: "memory");
            BAR();
        }
    }
    // write unnormalized partials (bf16): d = dt*32 + qd*8 + 4*hi + {0..3}
    const size_t pbase = (size_t)(b * SPLIT + sidx) * NN + q0;
    const size_t rowoff = (pbase + l31) * NCP;
    #pragma unroll
    for (int dt = 0; dt < 4; ++dt)
        #pragma unroll
        for (int qd = 0; qd < 4; ++qd) {
            unsigned int u0 = cvtpk(o[dt][qd * 4 + 0], o[dt][qd * 4 + 1]);
            unsigned int u1 = cvtpk(o[dt][qd * 4 + 2], o[dt][qd * 4 + 3]);
            *reinterpret_cast<uint2*>(&po[rowoff + dt * 32 + qd * 8 + hi * 4]) =
                make_uint2(u0, u1);
        }
    if (hi == 0) {
        mbuf[pbase + l31] = m_i;    // log2-domain running max
        lbuf[pbase + l31] = l_i;
    }
    if (doCT) {
        float* ctp = &ctg[((size_t)b * NK + blockIdx.x) * NCP + pd * 2];
        atomicAdd(ctp, ctx);
        atomicAdd(ctp + 1, cty);
    }
}

// ---------------- aug (merge fused): out = cam + ct . merge(po)^T ----------------
// Merge weights use exp2f (m stored in log2 domain).
__global__ __launch_bounds__(256) void aug_kernel(
    const float* __restrict__ cam, const float* __restrict__ ct,
    const unsigned short* __restrict__ po, const float* __restrict__ mbuf,
    const float* __restrict__ lbuf, float* __restrict__ out)
{
    const int b = blockIdx.y;
    const int tid = threadIdx.x, wid = tid >> 6, lane = tid & 63;
    const int lg = lane >> 4, lr = lane & 15;
    const int n0 = blockIdx.x * 64 + wid * 16;
    const int row = n0 + lr;
    const float* ctb = ct + (size_t)b * NK * NCP;

    float m_s[SPLIT], l_s[SPLIT];
    #pragma unroll
    for (int s = 0; s < SPLIT; ++s) {
        m_s[s] = mbuf[(size_t)(b * SPLIT + s) * NN + row];
        l_s[s] = lbuf[(size_t)(b * SPLIT + s) * NN + row];
    }
    uint4v pv[4][SPLIT];
    #pragma unroll
    for (int kk = 0; kk < 4; ++kk)
        #pragma unroll
        for (int s = 0; s < SPLIT; ++s)
            pv[kk][s] = *reinterpret_cast<const uint4v*>(
                &po[((size_t)(b * SPLIT + s) * NN + row) * NCP + kk * 32 + lg * 8]);

    float M = -INFINITY;
    #pragma unroll
    for (int s = 0; s < SPLIT; ++s) M = fmaxf(M, m_s[s]);
    float L = 0.f, wgt[SPLIT];
    #pragma unroll
    for (int s = 0; s < SPLIT; ++s) { wgt[s] = exp2f(m_s[s] - M); L += wgt[s] * l_s[s]; }
    const float inv = 1.f / L;
    #pragma unroll
    for (int s = 0; s < SPLIT; ++s) wgt[s] *= inv;

    f32x4 acc[2];
    acc[0] = (f32x4){0.f, 0.f, 0.f, 0.f};
    acc[1] = (f32x4){0.f, 0.f, 0.f, 0.f};
    #pragma unroll
    for (int kk = 0; kk < 4; ++kk) {
        float mg[8];
        #pragma unroll
        for (int j = 0; j < 8; ++j) mg[j] = 0.f;
        #pragma unroll
        for (int s = 0; s < SPLIT; ++s) {
            uint4v v = pv[kk][s];
            #pragma unroll
            for (int j = 0; j < 4; ++j) {
                mg[2 * j]     += wgt[s] * bf2f((unsigned short)(v[j] & 0xffff));
                mg[2 * j + 1] += wgt[s] * bf2f((unsigned short)(v[j] >> 16));
            }
        }
        uint4v au;
        #pragma unroll
        for (int j = 0; j < 4; ++j) au[j] = cvtpk(mg[2 * j], mg[2 * j + 1]);
        bf16x8 af = __builtin_bit_cast(bf16x8, au);
        #pragma unroll
        for (int c = 0; c < 2; ++c) {
            int k = c * 16 + lr;
            short8 bv;
            if (k < NK) {
                const float* cr = &ctb[(size_t)k * NCP + kk * 32 + lg * 8];
                #pragma unroll
                for (int j = 0; j < 8; ++j) bv[j] = (short)f2bf(cr[j]);
            } else {
                #pragma unroll
                for (int j = 0; j < 8; ++j) bv[j] = 0;
            }
            acc[c] = MFMA16(af, __builtin_bit_cast(bf16x8, bv), acc[c]);
        }
    }
    #pragma unroll
    for (int c = 0; c < 2; ++c) {
        int k = c * 16 + lr;
        if (k < NK) {
            #pragma unroll
            for (int i = 0; i < 4; ++i) {
                size_t off = ((size_t)b * NK + k) * NN + n0 + lg * 4 + i;
                out[off] = cam[off] + acc[c][i];
            }
        }
    }
}

extern "C" void kernel_launch(void* const* d_in, const int* in_sizes, int n_in,
                              void* d_out, int out_size, void* d_ws, size_t ws_size,
                              hipStream_t stream) {
    const float* feat = (const float*)d_in[0];
    const float* cam  = (const float*)d_in[1];
    const float* wpr  = (const float*)d_in[2];
    const float* bpr  = (const float*)d_in[3];
    float* out = (float*)d_out;

    const size_t MB = 1024 * 1024;
    char* ws = (char*)d_ws;
    unsigned short* fp  = (unsigned short*)(ws);                 // 4 MB
    unsigned short* fpT = (unsigned short*)(ws + 4 * MB);        // 4 MB
    float* ct           = (float*)(ws + 12 * MB);                // 40 KB
    unsigned short* po  = (unsigned short*)(ws + 13 * MB);       // 16 MB bf16 partial O
    float* mbuf         = (float*)(ws + 30 * MB);                // 256 KB
    float* lbuf         = (float*)(ws + 31 * MB);                // 256 KB

    proj_kernel<<<dim3(NN / 32, NB), 256, 0, stream>>>(feat, wpr, bpr, fp, fpT, ct);
    attn_partial_kernel<<<dim3(NN / 128, SPLIT, NB), 256, 0, stream>>>(
        fp, fpT, cam, ct, po, mbuf, lbuf);
    aug_kernel<<<dim3(NN / 64, NB), 256, 0, stream>>>(cam, ct, po, mbuf, lbuf, out);
}

// Round 22
// 82.337 us; speedup vs baseline: 1.0668x; 1.0668x over previous
//
#include <hip/hip_runtime.h>
#include <hip/hip_bf16.h>
#include <math.h>

#define NB 4
#define NC 512
#define NN 4096
#define NK 20
#define NCP 128
#define SPLIT 4
#define CHUNK (NN / SPLIT)   // 1024 keys per split
#define NTILES (CHUNK / 64)  // 16

typedef __bf16 bf16x8 __attribute__((ext_vector_type(8)));
typedef float f32x4 __attribute__((ext_vector_type(4)));
typedef float f32x16 __attribute__((ext_vector_type(16)));
typedef short short8 __attribute__((ext_vector_type(8)));
typedef unsigned int uint4v __attribute__((ext_vector_type(4)));

static __device__ __forceinline__ unsigned short f2bf(float f) {
    unsigned int u = __builtin_bit_cast(unsigned int, f);
    unsigned int r = (u + 0x7FFFu + ((u >> 16) & 1u)) >> 16;
    return (unsigned short)r;
}
static __device__ __forceinline__ float bf2f(unsigned short h) {
    unsigned int u = ((unsigned int)h) << 16;
    return __builtin_bit_cast(float, u);
}
static __device__ __forceinline__ bf16x8 ldbf8(const unsigned short* p) {
    return __builtin_bit_cast(bf16x8, *reinterpret_cast<const short8*>(p));
}
static __device__ __forceinline__ void gld16(const unsigned short* g, unsigned short* l) {
    __builtin_amdgcn_global_load_lds(
        (const __attribute__((address_space(1))) unsigned int*)g,
        (__attribute__((address_space(3))) unsigned int*)l, 16, 0, 0);
}
static __device__ __forceinline__ unsigned int cvtpk(float lo, float hi) {
    unsigned int r;
    asm("v_cvt_pk_bf16_f32 %0, %1, %2" : "=v"(r) : "v"(lo), "v"(hi));
    return r;
}

#define MFMA16(a, b, c) __builtin_amdgcn_mfma_f32_16x16x32_bf16(a, b, c, 0, 0, 0)
#define MFMA32(a, b, c) __builtin_amdgcn_mfma_f32_32x32x16_bf16(a, b, c, 0, 0, 0)
#define SCHED0() __builtin_amdgcn_sched_barrier(0)
#define BAR() do { SCHED0(); __builtin_amdgcn_s_barrier(); SCHED0(); } while (0)

// ---------------- proj: fp[b][n][d] = sum_c feat[b][c][n]*w[d][c] + bias[d] ----
// 32 n-rows per block -> grid 512 = 2 blocks/CU (w-reuse optimum). Block (0,0) zeroes ct.
__global__ __launch_bounds__(256) void proj_kernel(
    const float* __restrict__ feat, const float* __restrict__ w,
    const float* __restrict__ bias, unsigned short* __restrict__ fp,
    unsigned short* __restrict__ fpT, float* __restrict__ ctg)
{
    const int b = blockIdx.y;
    const int n0 = blockIdx.x * 32;
    const int tid = threadIdx.x;
    const int wid = tid >> 6;
    const int lane = tid & 63;
    const int lg = lane >> 4, lr = lane & 15;

    if (blockIdx.x == 0 && blockIdx.y == 0) {
        #pragma unroll
        for (int i = 0; i < (NB * NK * NCP) / 256; ++i)
            ctg[i * 256 + tid] = 0.f;
    }

    __shared__ unsigned short lds_f[2][32][40];   // dbuf [n][c] bf16, +8 pad

    const float* featb = feat + (size_t)b * NC * NN;

    f32x4 acc[2][2];
    #pragma unroll
    for (int i = 0; i < 2; ++i)
        #pragma unroll
        for (int j = 0; j < 2; ++j) acc[i][j] = (f32x4){0.f, 0.f, 0.f, 0.f};

    const int cc = tid >> 3, q = tid & 7;
    float4 pre = *reinterpret_cast<const float4*>(&featb[(size_t)cc * NN + n0 + q * 4]);

    for (int c0 = 0; c0 < NC; c0 += 32) {
        const int cur = (c0 >> 5) & 1;
        lds_f[cur][q * 4 + 0][cc] = f2bf(pre.x);
        lds_f[cur][q * 4 + 1][cc] = f2bf(pre.y);
        lds_f[cur][q * 4 + 2][cc] = f2bf(pre.z);
        lds_f[cur][q * 4 + 3][cc] = f2bf(pre.w);
        __syncthreads();
        if (c0 + 32 < NC)
            pre = *reinterpret_cast<const float4*>(
                &featb[(size_t)(c0 + 32 + cc) * NN + n0 + q * 4]);
        bf16x8 afr[2];
        #pragma unroll
        for (int dt = 0; dt < 2; ++dt) {
            const float4* wr = reinterpret_cast<const float4*>(
                w + (size_t)(wid * 32 + dt * 16 + lr) * NC + c0 + lg * 8);
            float4 w0 = wr[0], w1 = wr[1];
            short8 a;
            a[0] = (short)f2bf(w0.x); a[1] = (short)f2bf(w0.y);
            a[2] = (short)f2bf(w0.z); a[3] = (short)f2bf(w0.w);
            a[4] = (short)f2bf(w1.x); a[5] = (short)f2bf(w1.y);
            a[6] = (short)f2bf(w1.z); a[7] = (short)f2bf(w1.w);
            afr[dt] = __builtin_bit_cast(bf16x8, a);
        }
        #pragma unroll
        for (int n1 = 0; n1 < 2; ++n1) {
            bf16x8 bfr = ldbf8(&lds_f[cur][n1 * 16 + lr][lg * 8]);
            #pragma unroll
            for (int dt = 0; dt < 2; ++dt)
                acc[dt][n1] = MFMA16(afr[dt], bfr, acc[dt][n1]);
        }
    }
    #pragma unroll
    for (int dt = 0; dt < 2; ++dt)
        #pragma unroll
        for (int n1 = 0; n1 < 2; ++n1)
            #pragma unroll
            for (int i = 0; i < 4; ++i) {
                int d = wid * 32 + dt * 16 + lg * 4 + i;
                int n = n0 + n1 * 16 + lr;
                unsigned short h = f2bf(acc[dt][n1][i] + bias[d]);
                fp[((size_t)b * NN + n) * NCP + d] = h;
                fpT[((size_t)b * NCP + d) * NN + n] = h;
            }
}

// ---------------- attention partials + fused class_term ----------------
// 256 threads = 4 waves; wave owns 32 q-rows; 32x32x16 MFMA; R6 structure.
// Fused ct: cam in LDS; ct loads+FMAs after PV (execute while MFMA pipe drains).
// Last-tile prefetch guarded; final-tile drain+barrier removed (epilogue is
// register-only).
__global__ __launch_bounds__(256, 2) void attn_partial_kernel(
    const unsigned short* __restrict__ fp, const unsigned short* __restrict__ fpT,
    const float* __restrict__ cam, float* __restrict__ ctg,
    unsigned short* __restrict__ po, float* __restrict__ mbuf, float* __restrict__ lbuf)
{
    const int b = blockIdx.z;
    const int sidx = blockIdx.y;
    const int tid = threadIdx.x;
    const int wid = tid >> 6;
    const int lane = tid & 63;
    const int l31 = lane & 31, hi = lane >> 5;
    const int q0 = blockIdx.x * 128 + wid * 32;
    const int kvbase = sidx * CHUNK;

    __shared__ unsigned short kt[2][64 * 128];   // K dbuf: [kv][d], 16-chunk XOR (rk&15)
    __shared__ unsigned short vt[2][64 * 128];   // V dbuf: pair-rows [d>>1][256B], XOR (rowp&15)
    __shared__ float cam_lds[CHUNK];             // 4 KB cam chunk for fused ct

    const unsigned short* fpb  = fp  + (size_t)b * NN * NCP;
    const unsigned short* fpTb = fpT + (size_t)b * NCP * NN;

    const bool doCT = (blockIdx.x < NK);
    const int pd = tid & 63;          // d-pair index: d = 2*pd, 2*pd+1
    const int qtr = tid >> 6;         // n quarter within a 64-kv tile
    float ctx = 0.f, cty = 0.f;

    if (doCT) {
        const float* camb = cam + ((size_t)b * NK + blockIdx.x) * NN + kvbase;
        *reinterpret_cast<float4*>(&cam_lds[tid * 4]) =
            *reinterpret_cast<const float4*>(&camb[tid * 4]);
    }

    int offK[4], offV[4];
    #pragma unroll
    for (int i = 0; i < 4; ++i) {
        int oc = i * 256 + tid;
        int rk = oc >> 4, ck = oc & 15;
        offK[i] = rk * NCP + ((ck ^ (rk & 15)) << 3);
        int rowp = oc >> 4, cv = oc & 15;
        int cg = cv ^ (rowp & 15);
        int d = rowp * 2 + (cg >> 3), kvc = cg & 7;
        offV[i] = d * NN + (kvc << 3);
    }

    bf16x8 qf[8];
    #pragma unroll
    for (int kk = 0; kk < 8; ++kk)
        qf[kk] = ldbf8(&fpb[(size_t)(q0 + l31) * NCP + kk * 16 + hi * 8]);

    f32x16 o[4];
    #pragma unroll
    for (int dt = 0; dt < 4; ++dt)
        #pragma unroll
        for (int j = 0; j < 16; ++j) o[dt][j] = 0.f;
    float m_i = -INFINITY, l_i = 0.f;

    {
        const unsigned short* k0 = fpb + (size_t)kvbase * NCP;
        const unsigned short* v0 = fpTb + kvbase;
        #pragma unroll
        for (int i = 0; i < 4; ++i) {
            gld16(k0 + offK[i], &kt[0][(i * 256 + wid * 64) * 8]);
            gld16(v0 + offV[i], &vt[0][(i * 256 + wid * 64) * 8]);
        }
    }
    SCHED0();
    __syncthreads();   // drains vm+lgkm (staging + cam_lds writes) and barriers

    for (int t = 0; t < NTILES; ++t) {
        const int cur = t & 1;
        // ---- issue next-tile stages (guarded: no wasted wrap-around) ----
        if (t + 1 < NTILES) {
            const unsigned short* knext = fpb + (size_t)(kvbase + (t + 1) * 64) * NCP;
            const unsigned short* vnext = fpTb + kvbase + (t + 1) * 64;
            #pragma unroll
            for (int i = 0; i < 4; ++i) {
                gld16(knext + offK[i], &kt[cur ^ 1][(i * 256 + wid * 64) * 8]);
                gld16(vnext + offV[i], &vt[cur ^ 1][(i * 256 + wid * 64) * 8]);
            }
        }
        SCHED0();
        // ---- S^T = K Q^T ----
        const unsigned short* ktc = &kt[cur][0];
        f32x16 s[2];
        #pragma unroll
        for (int g = 0; g < 2; ++g)
            #pragma unroll
            for (int j = 0; j < 16; ++j) s[g][j] = 0.f;
        __builtin_amdgcn_s_setprio(1);
        #pragma unroll
        for (int kk = 0; kk < 8; ++kk) {
            #pragma unroll
            for (int g = 0; g < 2; ++g) {
                int row = g * 32 + l31;
                bf16x8 kf = ldbf8(&ktc[row * 128 + (((kk * 2 + hi) ^ (row & 15)) << 3)]);
                s[g] = MFMA32(kf, qf[kk], s[g]);
            }
        }
        __builtin_amdgcn_s_setprio(0);
        // ---- online softmax: lane owns q = l31 ----
        float pmax = s[0][0];
        #pragma unroll
        for (int g = 0; g < 2; ++g)
            #pragma unroll
            for (int j = 0; j < 16; ++j) pmax = fmaxf(pmax, s[g][j]);
        pmax = fmaxf(pmax, __shfl_xor(pmax, 32));
        if (!__all(pmax - m_i <= 8.f)) {   // defer-max (THR=8)
            float mnew = fmaxf(m_i, pmax);
            float sc = __expf(m_i - mnew);
            l_i *= sc;
            #pragma unroll
            for (int dt = 0; dt < 4; ++dt)
                #pragma unroll
                for (int j = 0; j < 16; ++j) o[dt][j] *= sc;
            m_i = mnew;
        }
        float sum = 0.f;
        #pragma unroll
        for (int g = 0; g < 2; ++g)
            #pragma unroll
            for (int j = 0; j < 16; ++j) {
                float e = __expf(s[g][j] - m_i);
                s[g][j] = e;
                sum += e;
            }
        sum += __shfl_xor(sum, 32);
        l_i += sum;
        // ---- P^T -> bf16 words -> register exchange (8 permlane32_swap) ----
        unsigned int wk[2][8];
        #pragma unroll
        for (int g = 0; g < 2; ++g)
            #pragma unroll
            for (int m = 0; m < 8; ++m)
                wk[g][m] = cvtpk(s[g][2 * m], s[g][2 * m + 1]);
        bf16x8 pf[4];
        #pragma unroll
        for (int g = 0; g < 2; ++g)
            #pragma unroll
            for (int sub = 0; sub < 2; ++sub) {
                unsigned int A0 = wk[g][4 * sub],     B0 = wk[g][4 * sub + 2];
                unsigned int A1 = wk[g][4 * sub + 1], B1 = wk[g][4 * sub + 3];
                asm("v_permlane32_swap_b32 %0, %1" : "+v"(A0), "+v"(B0));
                asm("v_permlane32_swap_b32 %0, %1" : "+v"(A1), "+v"(B1));
                uint4v u;
                u[0] = A0; u[1] = A1; u[2] = B0; u[3] = B1;
                pf[2 * g + sub] = __builtin_bit_cast(bf16x8, u);
            }
        // ---- O^T += V^T P^T ----
        const unsigned short* vtc = &vt[cur][0];
        __builtin_amdgcn_s_setprio(1);
        #pragma unroll
        for (int c2 = 0; c2 < 4; ++c2) {
            #pragma unroll
            for (int dt = 0; dt < 4; ++dt) {
                int row32 = dt * 32 + l31;
                int rowp = row32 >> 1;
                int chunk = (row32 & 1) * 8 + c2 * 2 + hi;
                bf16x8 vf = ldbf8(&vtc[rowp * 128 + ((chunk ^ (rowp & 15)) << 3)]);
                o[dt] = MFMA32(vf, pf[c2], o[dt]);
            }
        }
        __builtin_amdgcn_s_setprio(0);
        // ---- fused ct accumulation (cam from LDS, executes under MFMA drain) ----
        if (doCT) {
            float cf[16];
            const float4* cl = reinterpret_cast<const float4*>(&cam_lds[t * 64 + qtr * 16]);
            #pragma unroll
            for (int v4 = 0; v4 < 4; ++v4) {
                float4 c4 = cl[v4];
                cf[v4 * 4 + 0] = c4.x; cf[v4 * 4 + 1] = c4.y;
                cf[v4 * 4 + 2] = c4.z; cf[v4 * 4 + 3] = c4.w;
            }
            const int c8 = pd >> 2, de = (pd * 2) & 7;
            #pragma unroll
            for (int n = 0; n < 16; ++n) {
                int rown = qtr * 16 + n;
                unsigned int v = *reinterpret_cast<const unsigned int*>(
                    &ktc[rown * 128 + ((c8 ^ (rown & 15)) << 3) + de]);
                ctx += cf[n] * bf2f((unsigned short)(v & 0xffff));
                cty += cf[n] * bf2f((unsigned short)(v >> 16));
            }
        }
        SCHED0();
        if (t + 1 < NTILES) {   // final tile: nothing staged, no drain needed
            asm volatile("s_waitcnt vmcnt(0)" ::: "memory");
            BAR();
        }
    }
    // write unnormalized partials (bf16): d = dt*32 + qd*8 + 4*hi + {0..3}
    const size_t pbase = (size_t)(b * SPLIT + sidx) * NN + q0;
    const size_t rowoff = (pbase + l31) * NCP;
    #pragma unroll
    for (int dt = 0; dt < 4; ++dt)
        #pragma unroll
        for (int qd = 0; qd < 4; ++qd) {
            unsigned int u0 = cvtpk(o[dt][qd * 4 + 0], o[dt][qd * 4 + 1]);
            unsigned int u1 = cvtpk(o[dt][qd * 4 + 2], o[dt][qd * 4 + 3]);
            *reinterpret_cast<uint2*>(&po[rowoff + dt * 32 + qd * 8 + hi * 4]) =
                make_uint2(u0, u1);
        }
    if (hi == 0) {
        mbuf[pbase + l31] = m_i;
        lbuf[pbase + l31] = l_i;
    }
    if (doCT) {
        float* ctp = &ctg[((size_t)b * NK + blockIdx.x) * NCP + pd * 2];
        atomicAdd(ctp, ctx);
        atomicAdd(ctp + 1, cty);
    }
}

// ---------------- aug (merge fused): out = cam + ct . merge(po)^T ----------------
__global__ __launch_bounds__(256) void aug_kernel(
    const float* __restrict__ cam, const float* __restrict__ ct,
    const unsigned short* __restrict__ po, const float* __restrict__ mbuf,
    const float* __restrict__ lbuf, float* __restrict__ out)
{
    const int b = blockIdx.y;
    const int tid = threadIdx.x, wid = tid >> 6, lane = tid & 63;
    const int lg = lane >> 4, lr = lane & 15;
    const int n0 = blockIdx.x * 64 + wid * 16;
    const int row = n0 + lr;
    const float* ctb = ct + (size_t)b * NK * NCP;

    float m_s[SPLIT], l_s[SPLIT];
    #pragma unroll
    for (int s = 0; s < SPLIT; ++s) {
        m_s[s] = mbuf[(size_t)(b * SPLIT + s) * NN + row];
        l_s[s] = lbuf[(size_t)(b * SPLIT + s) * NN + row];
    }
    uint4v pv[4][SPLIT];
    #pragma unroll
    for (int kk = 0; kk < 4; ++kk)
        #pragma unroll
        for (int s = 0; s < SPLIT; ++s)
            pv[kk][s] = *reinterpret_cast<const uint4v*>(
                &po[((size_t)(b * SPLIT + s) * NN + row) * NCP + kk * 32 + lg * 8]);

    float M = -INFINITY;
    #pragma unroll
    for (int s = 0; s < SPLIT; ++s) M = fmaxf(M, m_s[s]);
    float L = 0.f, wgt[SPLIT];
    #pragma unroll
    for (int s = 0; s < SPLIT; ++s) { wgt[s] = __expf(m_s[s] - M); L += wgt[s] * l_s[s]; }
    const float inv = 1.f / L;
    #pragma unroll
    for (int s = 0; s < SPLIT; ++s) wgt[s] *= inv;

    f32x4 acc[2];
    acc[0] = (f32x4){0.f, 0.f, 0.f, 0.f};
    acc[1] = (f32x4){0.f, 0.f, 0.f, 0.f};
    #pragma unroll
    for (int kk = 0; kk < 4; ++kk) {
        float mg[8];
        #pragma unroll
        for (int j = 0; j < 8; ++j) mg[j] = 0.f;
        #pragma unroll
        for (int s = 0; s < SPLIT; ++s) {
            uint4v v = pv[kk][s];
            #pragma unroll
            for (int j = 0; j < 4; ++j) {
                mg[2 * j]     += wgt[s] * bf2f((unsigned short)(v[j] & 0xffff));
                mg[2 * j + 1] += wgt[s] * bf2f((unsigned short)(v[j] >> 16));
            }
        }
        uint4v au;
        #pragma unroll
        for (int j = 0; j < 4; ++j) au[j] = cvtpk(mg[2 * j], mg[2 * j + 1]);
        bf16x8 af = __builtin_bit_cast(bf16x8, au);
        #pragma unroll
        for (int c = 0; c < 2; ++c) {
            int k = c * 16 + lr;
            short8 bv;
            if (k < NK) {
                const float* cr = &ctb[(size_t)k * NCP + kk * 32 + lg * 8];
                #pragma unroll
                for (int j = 0; j < 8; ++j) bv[j] = (short)f2bf(cr[j]);
            } else {
                #pragma unroll
                for (int j = 0; j < 8; ++j) bv[j] = 0;
            }
            acc[c] = MFMA16(af, __builtin_bit_cast(bf16x8, bv), acc[c]);
        }
    }
    #pragma unroll
    for (int c = 0; c < 2; ++c) {
        int k = c * 16 + lr;
        if (k < NK) {
            #pragma unroll
            for (int i = 0; i < 4; ++i) {
                size_t off = ((size_t)b * NK + k) * NN + n0 + lg * 4 + i;
                out[off] = cam[off] + acc[c][i];
            }
        }
    }
}

extern "C" void kernel_launch(void* const* d_in, const int* in_sizes, int n_in,
                              void* d_out, int out_size, void* d_ws, size_t ws_size,
                              hipStream_t stream) {
    const float* feat = (const float*)d_in[0];
    const float* cam  = (const float*)d_in[1];
    const float* wpr  = (const float*)d_in[2];
    const float* bpr  = (const float*)d_in[3];
    float* out = (float*)d_out;

    const size_t MB = 1024 * 1024;
    char* ws = (char*)d_ws;
    unsigned short* fp  = (unsigned short*)(ws);                 // 4 MB
    unsigned short* fpT = (unsigned short*)(ws + 4 * MB);        // 4 MB
    float* ct           = (float*)(ws + 12 * MB);                // 40 KB
    unsigned short* po  = (unsigned short*)(ws + 13 * MB);       // 16 MB bf16 partial O
    float* mbuf         = (float*)(ws + 30 * MB);                // 256 KB
    float* lbuf         = (float*)(ws + 31 * MB);                // 256 KB

    proj_kernel<<<dim3(NN / 32, NB), 256, 0, stream>>>(feat, wpr, bpr, fp, fpT, ct);
    attn_partial_kernel<<<dim3(NN / 128, SPLIT, NB), 256, 0, stream>>>(
        fp, fpT, cam, ct, po, mbuf, lbuf);
    aug_kernel<<<dim3(NN / 64, NB), 256, 0, stream>>>(cam, ct, po, mbuf, lbuf, out);
}